// Round 1
// baseline (189.026 us; speedup 1.0000x reference)
//
#include <hip/hip_runtime.h>
#include <math.h>

// CRPS reduction kernel for MI355X (gfx950).
// B = 8388608 rows. Inputs:
//   d_in[0]: pred_params (B,2) f32  -> mu = [:,0], sigma2 = exp([:,1])
//   d_in[1]: tgts        (B,2) f32  -> tte = [:,0], censor = [:,1]
//   d_in[2]: ages        (B,)  f32
//   d_in[3]: use_intvl   int scalar (device)
// Output: d_out[0] = sum(crps)/B  (f32 scalar)

#define AGE_MAX_F     120.0f
#define INV_SQRT_PI_F 0.5641895835477563f
#define INV_SQRT_2PI_F 0.3989422804014327f
#define INV_SQRT_2_F  0.7071067811865476f
#define SQRT_2_F      1.4142135623730951f
#define B_TOTAL       8388608.0f

__device__ __forceinline__ float ndtr_f(float z) {
    return 0.5f * (1.0f + erff(z * INV_SQRT_2_F));
}

__global__ __launch_bounds__(256) void crps_kernel(
    const float4* __restrict__ pp,   // pred_params as pairs: (mu0, ls0, mu1, ls1)
    const float4* __restrict__ tg,   // tgts as pairs: (tte0, cen0, tte1, cen1)
    const float2* __restrict__ ag,   // ages pairs
    const int*    __restrict__ use_intvl_p,
    float*        __restrict__ out,
    int npairs, float inv_total)
{
    const int tid    = blockIdx.x * blockDim.x + threadIdx.x;
    const int stride = gridDim.x * blockDim.x;
    const int use_intvl = *use_intvl_p;   // uniform scalar load

    float acc = 0.0f;

    for (int i = tid; i < npairs; i += stride) {
        const float4 p = pp[i];
        const float4 t = tg[i];
        const float2 a = ag[i];

        #pragma unroll
        for (int j = 0; j < 2; ++j) {
            const float mu  = j ? p.z : p.x;
            const float ls  = j ? p.w : p.y;   // log sigma^2
            const float tte = j ? t.z : t.x;
            const float cen = j ? t.w : t.y;
            const float age = j ? a.y : a.x;

            const float s     = __expf( 0.5f * ls);   // sqrt(sigma2)
            const float inv_s = __expf(-0.5f * ls);   // 1/sqrt(sigma2)
            const float Y     = __logf(tte);

            // I(Y) with +mu; shares all transcendentals with I_(-Y):
            //   ystd' = -ystd, ncdf' = 1-ncdf, n2cdf' = 1-n2cdf, same pdf.
            const float dy  = Y - mu;
            const float z   = dy * inv_s;
            const float c   = ndtr_f(z);
            const float pdf = __expf(-0.5f * z * z) * INV_SQRT_2PI_F;
            const float c2  = ndtr_f(z * SQRT_2_F);

            // I(y) = (y-mu)*ncdf^2 + 2*s*ncdf*pdf - s*INV_SQRT_PI*n2cdf
            const float IY  =  dy * c * c
                             + 2.0f * s * c * pdf
                             - s * INV_SQRT_PI_F * c2;
            const float omc  = 1.0f - c;
            const float omc2 = 1.0f - c2;
            const float InY  = -dy * omc * omc
                             + 2.0f * s * omc * pdf
                             - s * INV_SQRT_PI_F * omc2;

            float crps;
            if (use_intvl) {
                const float T   = __logf(AGE_MAX_F - age);
                const float dt  = mu - T;             // (-T) - (-mu)
                const float zt  = dt * inv_s;
                const float ct  = ndtr_f(zt);
                const float pt  = __expf(-0.5f * zt * zt) * INV_SQRT_2PI_F;
                const float c2t = ndtr_f(zt * SQRT_2_F);
                const float InT =  dt * ct * ct
                                 + 2.0f * s * ct * pt
                                 - s * INV_SQRT_PI_F * c2t;
                crps = IY + InT + (1.0f - cen) * (InY - InT);
            } else {
                crps = IY + (1.0f - cen) * InY;
            }
            acc += crps;
        }
    }

    // wave64 shuffle reduce
    #pragma unroll
    for (int off = 32; off > 0; off >>= 1)
        acc += __shfl_down(acc, off);

    __shared__ float wsum[4];
    const int lane = threadIdx.x & 63;
    const int wid  = threadIdx.x >> 6;
    if (lane == 0) wsum[wid] = acc;
    __syncthreads();
    if (threadIdx.x == 0) {
        const float blocksum = wsum[0] + wsum[1] + wsum[2] + wsum[3];
        atomicAdd(out, blocksum * inv_total);
    }
}

extern "C" void kernel_launch(void* const* d_in, const int* in_sizes, int n_in,
                              void* d_out, int out_size, void* d_ws, size_t ws_size,
                              hipStream_t stream) {
    const float4* pp = (const float4*)d_in[0];
    const float4* tg = (const float4*)d_in[1];
    const float2* ag = (const float2*)d_in[2];
    const int*    ui = (const int*)d_in[3];
    float* out = (float*)d_out;

    const int n      = in_sizes[2];      // B (ages element count)
    const int npairs = n >> 1;
    const float inv_total = 1.0f / (float)n;

    // d_out is poisoned to 0xAA before every timed launch — zero it.
    hipMemsetAsync(d_out, 0, sizeof(float), stream);

    int blocks = (npairs + 255) / 256;
    if (blocks > 2048) blocks = 2048;
    crps_kernel<<<blocks, 256, 0, stream>>>(pp, tg, ag, ui, out, npairs, inv_total);
}

// Round 2
// 181.911 us; speedup vs baseline: 1.0391x; 1.0391x over previous
//
#include <hip/hip_runtime.h>
#include <math.h>

// CRPS reduction kernel for MI355X (gfx950), round 2.
// Branchless Zelen-Severo ndtr (reuses the pdf), no erff; phi(z*sqrt2) from
// pdf^2 (no extra exp); grid-stride unroll-by-2 for ILP.
//
//   d_in[0]: pred_params (B,2) f32  -> mu = [:,0], ls = [:,1] (sigma2 = exp(ls))
//   d_in[1]: tgts        (B,2) f32  -> tte = [:,0], censor = [:,1]
//   d_in[2]: ages        (B,)  f32
//   d_in[3]: use_intvl   int scalar (device)
// Output: d_out[0] = sum(crps)/B  (f32 scalar)

#define AGE_MAX_F      120.0f
#define INV_SQRT_PI_F  0.5641895835477563f
#define INV_SQRT_2PI_F 0.3989422804014327f
#define SQRT_2PI_F     2.5066282746310002f
#define SQRT_2_F       1.4142135623730951f

// Phi(z) given phi = standard normal pdf at z. Abramowitz-Stegun 26.2.17,
// |err| < 7.5e-8, fully branchless (sign handled via copysign fma).
__device__ __forceinline__ float ndtr_from_pdf(float z, float phi) {
    const float za = fabsf(z);
    const float t  = __builtin_amdgcn_rcpf(fmaf(0.2316419f, za, 1.0f));
    float p = fmaf(1.330274429f, t, -1.821255978f);
    p = fmaf(p, t, 1.781477937f);
    p = fmaf(p, t, -0.356563782f);
    p = fmaf(p, t, 0.319381530f);
    p = p * t;
    const float hm = fmaf(-phi, p, 0.5f);          // Phi(|z|) - 0.5
    return fmaf(copysignf(1.0f, z), hm, 0.5f);     // Phi(z)
}

// One (mu, ls, tte, cen, age) element -> crps contribution.
__device__ __forceinline__ float crps_elem(float mu, float ls, float tte,
                                           float cen, float age, int use_intvl) {
    const float s     = __expf( 0.5f * ls);   // sqrt(sigma2)
    const float inv_s = __expf(-0.5f * ls);   // 1/sqrt(sigma2)
    const float Y     = __logf(tte);

    const float dy  = Y - mu;
    const float z   = dy * inv_s;
    const float pdf = __expf(-0.5f * z * z) * INV_SQRT_2PI_F;
    const float c   = ndtr_from_pdf(z, pdf);
    const float pdf2 = pdf * pdf * SQRT_2PI_F;      // phi(z*sqrt(2))
    const float c2  = ndtr_from_pdf(z * SQRT_2_F, pdf2);

    // I(y;mu)   =  dy*c^2      + 2*s*c*pdf         - s/sqrt(pi)*c2
    // I(-y;-mu) = -dy*(1-c)^2  + 2*s*(1-c)*pdf     - s/sqrt(pi)*(1-c2)
    const float sp  = s * INV_SQRT_PI_F;
    const float IY  = dy * c * c + 2.0f * s * c * pdf - sp * c2;
    const float omc = 1.0f - c;
    const float InY = -dy * omc * omc + 2.0f * s * omc * pdf - sp * (1.0f - c2);

    if (use_intvl) {
        const float T    = __logf(AGE_MAX_F - age);
        const float dt   = mu - T;                  // argument of I_(-T)
        const float zt   = dt * inv_s;
        const float pdft = __expf(-0.5f * zt * zt) * INV_SQRT_2PI_F;
        const float ct   = ndtr_from_pdf(zt, pdft);
        const float pdft2 = pdft * pdft * SQRT_2PI_F;
        const float c2t  = ndtr_from_pdf(zt * SQRT_2_F, pdft2);
        const float InT  = dt * ct * ct + 2.0f * s * ct * pdft - sp * c2t;
        return IY + InT + (1.0f - cen) * (InY - InT);
    } else {
        return IY + (1.0f - cen) * InY;
    }
}

__device__ __forceinline__ float crps_pair(float4 p, float4 t, float2 a, int ui) {
    return crps_elem(p.x, p.y, t.x, t.y, a.x, ui)
         + crps_elem(p.z, p.w, t.z, t.w, a.y, ui);
}

__global__ __launch_bounds__(256) void crps_kernel(
    const float4* __restrict__ pp,
    const float4* __restrict__ tg,
    const float2* __restrict__ ag,
    const int*    __restrict__ use_intvl_p,
    float*        __restrict__ out,
    int npairs, float inv_total)
{
    const int tid    = blockIdx.x * blockDim.x + threadIdx.x;
    const int stride = gridDim.x * blockDim.x;
    const int ui     = *use_intvl_p;

    float acc = 0.0f;

    int i = tid;
    // unroll-by-2: two independent element-pair chains in flight (4 elements)
    for (; i + stride < npairs; i += 2 * stride) {
        const float4 p0 = pp[i];
        const float4 t0 = tg[i];
        const float2 a0 = ag[i];
        const float4 p1 = pp[i + stride];
        const float4 t1 = tg[i + stride];
        const float2 a1 = ag[i + stride];
        acc += crps_pair(p0, t0, a0, ui);
        acc += crps_pair(p1, t1, a1, ui);
    }
    for (; i < npairs; i += stride) {
        acc += crps_pair(pp[i], tg[i], ag[i], ui);
    }

    // wave64 shuffle reduce
    #pragma unroll
    for (int off = 32; off > 0; off >>= 1)
        acc += __shfl_down(acc, off);

    __shared__ float wsum[4];
    const int lane = threadIdx.x & 63;
    const int wid  = threadIdx.x >> 6;
    if (lane == 0) wsum[wid] = acc;
    __syncthreads();
    if (threadIdx.x == 0) {
        const float blocksum = wsum[0] + wsum[1] + wsum[2] + wsum[3];
        atomicAdd(out, blocksum * inv_total);
    }
}

extern "C" void kernel_launch(void* const* d_in, const int* in_sizes, int n_in,
                              void* d_out, int out_size, void* d_ws, size_t ws_size,
                              hipStream_t stream) {
    const float4* pp = (const float4*)d_in[0];
    const float4* tg = (const float4*)d_in[1];
    const float2* ag = (const float2*)d_in[2];
    const int*    ui = (const int*)d_in[3];
    float* out = (float*)d_out;

    const int n      = in_sizes[2];      // B
    const int npairs = n >> 1;
    const float inv_total = 1.0f / (float)n;

    hipMemsetAsync(d_out, 0, sizeof(float), stream);

    int blocks = (npairs + 255) / 256;
    if (blocks > 2048) blocks = 2048;
    crps_kernel<<<blocks, 256, 0, stream>>>(pp, tg, ag, ui, out, npairs, inv_total);
}